// Round 1
// baseline (131.231 us; speedup 1.0000x reference)
//
#include <hip/hip_runtime.h>

// Problem constants (from reference setup_inputs)
#define BB 4
#define CC 12
#define DD 8
#define HG 16
#define WG 16
#define HH 1024
#define WW 1024

// Native 4-float vector (clang ext vector) — legal operand for
// __builtin_nontemporal_load/store.
typedef float vf4 __attribute__((ext_vector_type(4)));

// LDS slab layout per row: S[x*XSTRIDE + z*CC + c], y-interpolation pre-folded.
// XSTRIDE = 8*12 + 8 pad floats = 104 -> cells stay 16B-aligned and
// bank = (8x + 12z + c) % 32 spreads the guide-random z across banks.
#define XSTRIDE 104
#define ROWS 4   // rows per block; 4-aligned groups never straddle an fy band
#define NSTG 6   // CC*DD*WG / 256 staging cells per thread

__global__ __launch_bounds__(256, 4) void slice_apply(
    const float* __restrict__ grid,   // [B,C,D,HG,WG]
    const float* __restrict__ guide,  // [B,H,W]
    const float* __restrict__ img,    // [B,3,H,W]
    float* __restrict__ out)          // [B,3,H,W]
{
    __shared__ float S[ROWS * WG * XSTRIDE];  // 4 * 6656 B = 26624 B

    const int blk = blockIdx.x;
    const int b  = blk >> 8;                 // HH/ROWS = 256 row-groups per batch
    const int h0 = (blk & 255) * ROWS;

    // y-cell pair shared by all ROWS rows of this block
    const float gy0 = (h0 + 0.5f) * ((float)HG / (float)HH);
    const float fy  = floorf(gy0 - 0.5f);
    const int   iy0 = max(0, min(HG - 1, (int)fy));
    const int   iy1 = max(0, min(HG - 1, (int)fy + 1));

    float wy1r[ROWS];
    #pragma unroll
    for (int r = 0; r < ROWS; ++r) {
        const float gy = (h0 + r + 0.5f) * ((float)HG / (float)HH);
        wy1r[r] = gy - 0.5f - fy;           // ty in [0,1)
    }

    // ---- Phase 1: issue the block's 12 grid loads FIRST (oldest in the
    // vmem queue; mostly L2/L1-resident). Flat index ordered (c,z,x) so
    // consecutive threads read consecutive x (coalesced 64B segments).
    float v0[NSTG], v1[NSTG];
    int   so[NSTG];
    #pragma unroll
    for (int t = 0; t < NSTG; ++t) {
        const int j = (int)threadIdx.x + t * 256;
        const int x = j & 15;
        const int z = (j >> 4) & 7;
        const int c = j >> 7;
        const size_t base = ((size_t)(b * CC + c) * DD + z) * (HG * WG);
        v0[t] = grid[base + iy0 * WG + x];
        v1[t] = grid[base + iy1 * WG + x];
        so[t] = x * XSTRIDE + z * CC + c;
    }

    // ---- Phase 2: issue ALL 16 guide/image vector loads for the 4 rows
    // up front (4 KB in flight per wave). Their latency hides under the
    // staging waits + barrier; each row's compute later peels them off the
    // queue via compiler-counted vmcnt(12/8/4/0).
    const int w0 = (int)threadIdx.x * 4;
    vf4 g4[ROWS], i0[ROWS], i1[ROWS], i2[ROWS];
    #pragma unroll
    for (int r = 0; r < ROWS; ++r) {
        const size_t pix = ((size_t)b * HH + (h0 + r)) * WW + w0;
        g4[r] = __builtin_nontemporal_load(reinterpret_cast<const vf4*>(guide + pix));
        const float* ib = img + (((size_t)b * 3) * HH + (h0 + r)) * WW + w0;
        i0[r] = __builtin_nontemporal_load(reinterpret_cast<const vf4*>(ib));
        i1[r] = __builtin_nontemporal_load(reinterpret_cast<const vf4*>(ib + (size_t)HH * WW));
        i2[r] = __builtin_nontemporal_load(reinterpret_cast<const vf4*>(ib + (size_t)2 * HH * WW));
    }

    // ---- Phase 3: fold the y-lerp into ROWS per-row slabs. The ds_writes
    // depend only on the Phase-1 grid loads -> s_waitcnt vmcnt(16) keeps
    // the Phase-2 loads in flight.
    #pragma unroll
    for (int t = 0; t < NSTG; ++t) {
        const float d = v1[t] - v0[t];
        #pragma unroll
        for (int r = 0; r < ROWS; ++r) {
            S[r * (WG * XSTRIDE) + so[t]] = v0[t] + wy1r[r] * d;
        }
    }
    __syncthreads();

    // x cell pair is uniform across the 4 pixels of this thread
    const float scale = (float)WG / (float)WW;       // 1/64
    const float gx0 = (w0 + 0.5f) * scale;
    const float fx  = floorf(gx0 - 0.5f);
    const float tx0 = gx0 - 0.5f - fx;
    const int   ix0 = max(0, min(WG - 1, (int)fx));
    const int   ix1 = max(0, min(WG - 1, (int)fx + 1));

    #pragma unroll
    for (int r = 0; r < ROWS; ++r) {
        const int h = h0 + r;
        const float* Sr  = S + r * (WG * XSTRIDE);
        const float* Sx0 = Sr + ix0 * XSTRIDE;
        const float* Sx1 = Sr + ix1 * XSTRIDE;

        vf4 o0, o1, o2;

        #pragma unroll
        for (int p = 0; p < 4; ++p) {
            const float tx  = tx0 + (float)p * scale;
            const float wx0 = 1.0f - tx, wx1 = tx;

            const float gv = g4[r][p];
            const float gz  = gv * (float)DD;
            const float fz  = floorf(gz - 0.5f);
            const float tz  = gz - 0.5f - fz;
            const int   iz0 = max(0, min(DD - 1, (int)fz));
            const int   iz1 = max(0, min(DD - 1, (int)fz + 1));
            const float wz0 = 1.0f - tz, wz1 = tz;

            const float w00 = wz0 * wx0, w01 = wz0 * wx1;
            const float w10 = wz1 * wx0, w11 = wz1 * wx1;

            float acc[12];
            #pragma unroll
            for (int k = 0; k < 12; ++k) acc[k] = 0.0f;

            auto accum = [&](const float* P, float w) {
                const vf4 a = *reinterpret_cast<const vf4*>(P);
                const vf4 e = *reinterpret_cast<const vf4*>(P + 4);
                const vf4 f = *reinterpret_cast<const vf4*>(P + 8);
                #pragma unroll
                for (int k = 0; k < 4; ++k) {
                    acc[k]     += w * a[k];
                    acc[4 + k] += w * e[k];
                    acc[8 + k] += w * f[k];
                }
            };
            accum(Sx0 + iz0 * CC, w00);
            accum(Sx1 + iz0 * CC, w01);
            accum(Sx0 + iz1 * CC, w10);
            accum(Sx1 + iz1 * CC, w11);

            const float im0 = i0[r][p];
            const float im1 = i1[r][p];
            const float im2 = i2[r][p];

            o0[p] = acc[0] * im0 + acc[1] * im1 + acc[2]  * im2 + acc[3];
            o1[p] = acc[4] * im0 + acc[5] * im1 + acc[6]  * im2 + acc[7];
            o2[p] = acc[8] * im0 + acc[9] * im1 + acc[10] * im2 + acc[11];
        }

        float* ob = out + (((size_t)b * 3) * HH + h) * WW + w0;
        __builtin_nontemporal_store(o0, reinterpret_cast<vf4*>(ob));
        __builtin_nontemporal_store(o1, reinterpret_cast<vf4*>(ob + (size_t)HH * WW));
        __builtin_nontemporal_store(o2, reinterpret_cast<vf4*>(ob + (size_t)2 * HH * WW));
    }
}

extern "C" void kernel_launch(void* const* d_in, const int* in_sizes, int n_in,
                              void* d_out, int out_size, void* d_ws, size_t ws_size,
                              hipStream_t stream) {
    const float* grid  = (const float*)d_in[0];
    const float* guide = (const float*)d_in[1];
    const float* image = (const float*)d_in[2];
    float* out = (float*)d_out;

    const int nblocks = BB * HH / ROWS;  // 1024 blocks, 4 rows each
    slice_apply<<<nblocks, 256, 0, stream>>>(grid, guide, image, out);
}

// Round 2
// 124.148 us; speedup vs baseline: 1.0571x; 1.0571x over previous
//
#include <hip/hip_runtime.h>

// Problem constants (from reference setup_inputs)
#define BB 4
#define CC 12
#define DD 8
#define HG 16
#define WG 16
#define HH 1024
#define WW 1024

// Native 4-float vector (clang ext vector) — legal operand for
// __builtin_nontemporal_load/store.
typedef float vf4 __attribute__((ext_vector_type(4)));

// LDS slab layout per row: S[x*XSTRIDE + z*CC + c], y-interpolation pre-folded.
// XSTRIDE = 8*12 + 8 pad floats = 104 -> cells stay 16B-aligned and
// bank = (8x + 12z + c) % 32 spreads the guide-random z across banks.
#define XSTRIDE 104
#define ROWS 2   // rows per block; grid = 2048 blocks = 8 blocks/CU supply
                 // (was 4 -> 1024 blocks = only 4 blocks/CU, grid-limited
                 // occupancy). Even h0 never straddles an fy band (bands
                 // flip at h == 32 mod 64).

__global__ __launch_bounds__(256) void slice_apply(
    const float* __restrict__ grid,   // [B,C,D,HG,WG]
    const float* __restrict__ guide,  // [B,H,W]
    const float* __restrict__ img,    // [B,3,H,W]
    float* __restrict__ out)          // [B,3,H,W]
{
    __shared__ float S[ROWS * WG * XSTRIDE];  // 2 * 6656 B = 13312 B

    const int blk = blockIdx.x;
    const int b  = blk >> 9;                 // HH/ROWS = 512 row-groups per batch
    const int h0 = (blk & 511) * ROWS;

    // y-cell pair shared by all ROWS rows of this block
    const float gy0 = (h0 + 0.5f) * ((float)HG / (float)HH);
    const float fy  = floorf(gy0 - 0.5f);
    const int   iy0 = max(0, min(HG - 1, (int)fy));
    const int   iy1 = max(0, min(HG - 1, (int)fy + 1));

    float wy1r[ROWS];
    #pragma unroll
    for (int r = 0; r < ROWS; ++r) {
        const float gy = (h0 + r + 0.5f) * ((float)HG / (float)HH);
        wy1r[r] = gy - 0.5f - fy;           // ty in [0,1)
    }

    // Stage: load the two raw y-slices once, fold into ROWS per-row slabs.
    // 1536 cells; flat index ordered (c,z,x) so consecutive threads read
    // consecutive x (coalesced 64B segments).
    for (int j = threadIdx.x; j < CC * DD * WG; j += 256) {
        const int x = j & 15;
        const int z = (j >> 4) & 7;
        const int c = j >> 7;
        const size_t base = ((size_t)(b * CC + c) * DD + z) * (HG * WG);
        const float v0 = grid[base + iy0 * WG + x];
        const float v1 = grid[base + iy1 * WG + x];
        const int so = x * XSTRIDE + z * CC + c;
        #pragma unroll
        for (int r = 0; r < ROWS; ++r) {
            const float ty = wy1r[r];
            S[r * (WG * XSTRIDE) + so] = v0 + ty * (v1 - v0);
        }
    }
    __syncthreads();

    const int w0 = threadIdx.x * 4;

    // x cell pair is uniform across the 4 pixels of this thread
    const float scale = (float)WG / (float)WW;       // 1/64
    const float gx0 = (w0 + 0.5f) * scale;
    const float fx  = floorf(gx0 - 0.5f);
    const float tx0 = gx0 - 0.5f - fx;
    const int   ix0 = max(0, min(WG - 1, (int)fx));
    const int   ix1 = max(0, min(WG - 1, (int)fx + 1));

    #pragma unroll
    for (int r = 0; r < ROWS; ++r) {
        const int h = h0 + r;
        const float* Sr  = S + r * (WG * XSTRIDE);
        const float* Sx0 = Sr + ix0 * XSTRIDE;
        const float* Sx1 = Sr + ix1 * XSTRIDE;

        const size_t pix = ((size_t)b * HH + h) * WW + w0;
        const vf4 g4 = *reinterpret_cast<const vf4*>(guide + pix);
        const float* ib = img + (((size_t)b * 3) * HH + h) * WW + w0;
        const vf4 i0 = __builtin_nontemporal_load(reinterpret_cast<const vf4*>(ib));
        const vf4 i1 = __builtin_nontemporal_load(reinterpret_cast<const vf4*>(ib + (size_t)HH * WW));
        const vf4 i2 = __builtin_nontemporal_load(reinterpret_cast<const vf4*>(ib + (size_t)2 * HH * WW));

        vf4 o0, o1, o2;

        #pragma unroll
        for (int p = 0; p < 4; ++p) {
            const float tx  = tx0 + (float)p * scale;
            const float wx0 = 1.0f - tx, wx1 = tx;

            const float gv = g4[p];
            const float gz  = gv * (float)DD;
            const float fz  = floorf(gz - 0.5f);
            const float tz  = gz - 0.5f - fz;
            const int   iz0 = max(0, min(DD - 1, (int)fz));
            const int   iz1 = max(0, min(DD - 1, (int)fz + 1));
            const float wz0 = 1.0f - tz, wz1 = tz;

            const float w00 = wz0 * wx0, w01 = wz0 * wx1;
            const float w10 = wz1 * wx0, w11 = wz1 * wx1;

            float acc[12];
            #pragma unroll
            for (int k = 0; k < 12; ++k) acc[k] = 0.0f;

            auto accum = [&](const float* P, float w) {
                const vf4 a = *reinterpret_cast<const vf4*>(P);
                const vf4 e = *reinterpret_cast<const vf4*>(P + 4);
                const vf4 f = *reinterpret_cast<const vf4*>(P + 8);
                #pragma unroll
                for (int k = 0; k < 4; ++k) {
                    acc[k]     += w * a[k];
                    acc[4 + k] += w * e[k];
                    acc[8 + k] += w * f[k];
                }
            };
            accum(Sx0 + iz0 * CC, w00);
            accum(Sx1 + iz0 * CC, w01);
            accum(Sx0 + iz1 * CC, w10);
            accum(Sx1 + iz1 * CC, w11);

            const float im0 = i0[p];
            const float im1 = i1[p];
            const float im2 = i2[p];

            o0[p] = acc[0] * im0 + acc[1] * im1 + acc[2]  * im2 + acc[3];
            o1[p] = acc[4] * im0 + acc[5] * im1 + acc[6]  * im2 + acc[7];
            o2[p] = acc[8] * im0 + acc[9] * im1 + acc[10] * im2 + acc[11];
        }

        float* ob = out + (((size_t)b * 3) * HH + h) * WW + w0;
        __builtin_nontemporal_store(o0, reinterpret_cast<vf4*>(ob));
        __builtin_nontemporal_store(o1, reinterpret_cast<vf4*>(ob + (size_t)HH * WW));
        __builtin_nontemporal_store(o2, reinterpret_cast<vf4*>(ob + (size_t)2 * HH * WW));
    }
}

extern "C" void kernel_launch(void* const* d_in, const int* in_sizes, int n_in,
                              void* d_out, int out_size, void* d_ws, size_t ws_size,
                              hipStream_t stream) {
    const float* grid  = (const float*)d_in[0];
    const float* guide = (const float*)d_in[1];
    const float* image = (const float*)d_in[2];
    float* out = (float*)d_out;

    const int nblocks = BB * HH / ROWS;  // 2048 blocks, 2 rows each
    slice_apply<<<nblocks, 256, 0, stream>>>(grid, guide, image, out);
}